// Round 3
// baseline (1897.368 us; speedup 1.0000x reference)
//
#include <hip/hip_runtime.h>
#include <stdint.h>

typedef unsigned short u16;
typedef __attribute__((ext_vector_type(8))) short bf16x8;
typedef __attribute__((ext_vector_type(4))) float f32x4;

#define NPTS 65536
#define NK27 27
#define KNN 16

__device__ __forceinline__ u16 f2b(float f) {
  union { float f; uint32_t u; } v; v.f = f;
  uint32_t r = (v.u + 0x7fffu + ((v.u >> 16) & 1u)) >> 16;
  return (u16)r;
}
__device__ __forceinline__ float b2f(u16 h) {
  union { uint32_t u; float f; } v; v.u = ((uint32_t)h) << 16; return v.f;
}

// dst[g][co][ci] (bf16) = src[g][ci][co] (f32); id is dst-linear (coalesced writes)
__global__ __launch_bounds__(256) void wtrans(const float* __restrict__ src, u16* __restrict__ dst,
                                              int G, int CI, int CO) {
  int id = blockIdx.x * 256 + threadIdx.x;
  int tot = G * CI * CO;
  if (id >= tot) return;
  int g = id / (CI * CO);
  int r = id - g * (CI * CO);
  int co = r / CI;
  int ci = r - co * CI;
  dst[id] = f2b(src[(size_t)g * CI * CO + (size_t)ci * CO + co]);
}

__global__ void zero_pads(u16* a, u16* b, u16* c, u16* d, u16* e) {
  int t = threadIdx.x;
  if (t < 128) { a[t] = 0; b[t] = 0; c[t] = 0; }
  if (t < 32) { d[t] = 0; e[t] = 0; }
}

// out[n,co] = b[co] + sum_k feats[idx[n,k]] * W[k,0,co]   (idx==NPTS -> 0)
__global__ __launch_bounds__(256) void conv_in_k(const float* __restrict__ feats, const int* __restrict__ idx,
                                                 const float* __restrict__ W, const float* __restrict__ b,
                                                 u16* __restrict__ out) {
  int t = blockIdx.x * 256 + threadIdx.x;
  int n = t >> 7;
  int co = t & 127;
  float acc = b[co];
  for (int k = 0; k < NK27; ++k) {
    int m = idx[n * NK27 + k];
    float f = (m < NPTS) ? feats[m] : 0.0f;
    acc += f * W[k * 128 + co];
  }
  out[(size_t)n * 128 + co] = f2b(acc);
}

#define GLDS16(g, l)                                                                        \
  __builtin_amdgcn_global_load_lds((const __attribute__((address_space(1))) void*)(g),      \
                                   (__attribute__((address_space(3))) void*)(l), 16, 0, 0)

// Gathered GEMM: y[n, :] (+epilogue) = sum_ko  x[idx[n,ko], :] @ Wt[ko]^T
// x: [NPTS+1][CIN] bf16 (row NPTS zero); Wt: [NK][COUT][CIN] bf16 (pre-transposed)
// EMODE: 0=none 1=relu(v) 2=relu(v+res) 3=relu(v)+res   (v includes bias)
// Per tap: [B-frag loads (oldest in vmcnt FIFO)] -> [gathers k+1] -> [ds_read+MFMA].
// B consumption then never waits on gather retirement (vmcnt is in-order).
template<int CIN, int COUT, int NK, int EMODE, bool OUTF32>
__global__ __launch_bounds__(512)
void sconv(const u16* __restrict__ x, const int* __restrict__ idx,
           const u16* __restrict__ Wt, const float* __restrict__ bias,
           const u16* __restrict__ res, int res_stride,
           void* __restrict__ yout, int out_stride) {
  constexpr int BM = 128;
  constexpr int CPR = CIN / 8;             // 16B chunks per row
  constexpr int RPI = 64 / CPR;            // rows per global_load_lds issue
  constexpr int IPW = BM / (RPI * 8);      // issues per wave (8 waves)
  constexpr int SWZ = (CPR < 8 ? CPR : 8) - 1;
  constexpr int WAVES_N = COUT / 32;       // 1,2,4
  constexpr int WAVES_M = 8 / WAVES_N;
  constexpr int WM = BM / WAVES_M;         // 16,32,64
  constexpr int M_REP = WM / 16;
  constexpr int N_REP = 2;
  constexpr int KK = CIN / 32;

  __shared__ __attribute__((aligned(16))) u16 As[2][BM * CIN];

  const int tid = threadIdx.x;
  const int lane = tid & 63;
  const int wave = tid >> 6;
  const int n0 = blockIdx.x * BM;
  const int lr = lane & 15;
  const int lh = lane >> 4;
  const int wn = wave % WAVES_N;
  const int wm = wave / WAVES_N;
  const int row0 = wm * WM;
  const int col0 = wn * 32;
  const int lsub = lane / CPR;             // sub-row within issue
  const int lchunk = lane & (CPR - 1);     // linear chunk slot this lane fills

  int r_loc[IPW];
  int csrc[IPW];
#pragma unroll
  for (int i = 0; i < IPW; ++i) {
    r_loc[i] = wave * 16 + i * RPI + lsub;
    csrc[i] = lchunk ^ (r_loc[i] & SWZ);   // inverse swizzle on the SOURCE
  }

  int mnxt[IPW];
  {
    int m0[IPW];
#pragma unroll
    for (int i = 0; i < IPW; ++i)
      m0[i] = (NK == 1) ? (n0 + r_loc[i]) : idx[(n0 + r_loc[i]) * NK27 + 0];
#pragma unroll
    for (int i = 0; i < IPW; ++i)
      GLDS16(x + (size_t)m0[i] * CIN + csrc[i] * 8, &As[0][(wave * 16 + i * RPI) * CIN]);
  }
  if (NK > 1) {
#pragma unroll
    for (int i = 0; i < IPW; ++i)
      mnxt[i] = idx[(n0 + r_loc[i]) * NK27 + 1];
  }

  f32x4 acc[M_REP][N_REP];
#pragma unroll
  for (int i = 0; i < M_REP; ++i)
#pragma unroll
    for (int j = 0; j < N_REP; ++j) acc[i][j] = (f32x4){0.f, 0.f, 0.f, 0.f};

  int cur = 0;
  for (int k = 0; k < NK; ++k) {
    __syncthreads();  // publishes As[cur] (drains each wave's own gathers for it)

    // 1) B fragments for THIS tap — issued first so they are the oldest
    //    entries in the vmcnt FIFO (never wait on the gathers below).
    const u16* wko = Wt + (size_t)k * (COUT * CIN);
    bf16x8 bfr[KK][N_REP];
#pragma unroll
    for (int kk = 0; kk < KK; ++kk)
#pragma unroll
      for (int nr = 0; nr < N_REP; ++nr)
        bfr[kk][nr] = *(const bf16x8*)(wko + (size_t)(col0 + nr * 16 + lr) * CIN + kk * 32 + lh * 8);
    __builtin_amdgcn_sched_barrier(0);

    // 2) gathers for tap k+1 into the other buffer (full compute phase to land)
    if (k + 1 < NK) {
#pragma unroll
      for (int i = 0; i < IPW; ++i)
        GLDS16(x + (size_t)mnxt[i] * CIN + csrc[i] * 8,
               &As[cur ^ 1][(wave * 16 + i * RPI) * CIN]);
      if (k + 2 < NK) {
#pragma unroll
        for (int i = 0; i < IPW; ++i)
          mnxt[i] = idx[(n0 + r_loc[i]) * NK27 + (k + 2)];
      }
    }
    __builtin_amdgcn_sched_barrier(0);

    // 3) compute from LDS buf[cur] + bfr
#pragma unroll
    for (int kk = 0; kk < KK; ++kk) {
      bf16x8 a[M_REP];
#pragma unroll
      for (int mr = 0; mr < M_REP; ++mr) {
        int ar = row0 + mr * 16 + lr;
        int pc = (kk * 4 + lh) ^ (ar & SWZ);   // swizzled read
        a[mr] = *(const bf16x8*)(&As[cur][ar * CIN + pc * 8]);
      }
#pragma unroll
      for (int mr = 0; mr < M_REP; ++mr)
#pragma unroll
        for (int nr = 0; nr < N_REP; ++nr)
          acc[mr][nr] = __builtin_amdgcn_mfma_f32_16x16x32_bf16(a[mr], bfr[kk][nr], acc[mr][nr], 0, 0, 0);
    }
    cur ^= 1;
  }

  // epilogue: C/D layout col=lane&15, row=(lane>>4)*4+j
#pragma unroll
  for (int mr = 0; mr < M_REP; ++mr) {
#pragma unroll
    for (int nr = 0; nr < N_REP; ++nr) {
      int col = col0 + nr * 16 + lr;
      float bv = bias ? bias[col] : 0.0f;
#pragma unroll
      for (int j = 0; j < 4; ++j) {
        int row = row0 + mr * 16 + lh * 4 + j;
        int n = n0 + row;
        float v = acc[mr][nr][j] + bv;
        if (EMODE == 1) v = fmaxf(v, 0.0f);
        else if (EMODE == 2) v = fmaxf(v + b2f(res[(size_t)n * res_stride + col]), 0.0f);
        else if (EMODE == 3) v = fmaxf(v, 0.0f) + b2f(res[(size_t)n * res_stride + col]);
        if (OUTF32) ((float*)yout)[(size_t)n * out_stride + col] = v;
        else ((u16*)yout)[(size_t)n * out_stride + col] = f2b(v);
      }
    }
  }
}

// one wave per point: logits = (q . k_j)/sqrt(128); softmax; agg = sum a_j v_j
__global__ __launch_bounds__(256)
void attn_k(const u16* __restrict__ qb, const u16* __restrict__ kb,
            const u16* __restrict__ vb, const int* __restrict__ knn,
            u16* __restrict__ agg) {
  int n = (blockIdx.x * 256 + threadIdx.x) >> 6;
  int lane = threadIdx.x & 63;
  int c0 = lane * 2;
  uint32_t qp = *(const uint32_t*)(qb + (size_t)n * 128 + c0);
  float q0 = b2f((u16)(qp & 0xffff)), q1 = b2f((u16)(qp >> 16));
  float lg[KNN];
  int ms[KNN];
#pragma unroll
  for (int j = 0; j < KNN; ++j) {
    int m = knn[n * KNN + j];
    ms[j] = m;
    uint32_t kp = *(const uint32_t*)(kb + (size_t)m * 128 + c0);
    float p = q0 * b2f((u16)(kp & 0xffff)) + q1 * b2f((u16)(kp >> 16));
#pragma unroll
    for (int d = 1; d < 64; d <<= 1) p += __shfl_xor(p, d);
    lg[j] = p * 0.08838834764831845f;  // 128^-0.5
  }
  float mx = lg[0];
#pragma unroll
  for (int j = 1; j < KNN; ++j) mx = fmaxf(mx, lg[j]);
  float s = 0.f, w[KNN];
#pragma unroll
  for (int j = 0; j < KNN; ++j) { w[j] = __expf(lg[j] - mx); s += w[j]; }
  float inv = 1.0f / s;
  float a0 = 0.f, a1 = 0.f;
#pragma unroll
  for (int j = 0; j < KNN; ++j) {
    uint32_t vp = *(const uint32_t*)(vb + (size_t)ms[j] * 128 + c0);
    a0 += w[j] * b2f((u16)(vp & 0xffff));
    a1 += w[j] * b2f((u16)(vp >> 16));
  }
  a0 *= inv; a1 *= inv;
  uint32_t op = (uint32_t)f2b(a0) | ((uint32_t)f2b(a1) << 16);
  *(uint32_t*)(agg + (size_t)n * 128 + c0) = op;
}

extern "C" void kernel_launch(void* const* d_in, const int* in_sizes, int n_in,
                              void* d_out, int out_size, void* d_ws, size_t ws_size,
                              hipStream_t stream) {
  (void)in_sizes; (void)n_in; (void)out_size; (void)ws_size;
  const float* feats = (const float*)d_in[0];
  const int*   nbr   = (const int*)d_in[1];
  const int*   knn   = (const int*)d_in[2];
  const float* W_in  = (const float*)d_in[3];
  const float* b_in  = (const float*)d_in[4];
  const float* W_c0  = (const float*)d_in[5];
  const float* b_c0  = (const float*)d_in[6];
  const float* W_c1  = (const float*)d_in[7];
  const float* b_c1  = (const float*)d_in[8];
  const float* Wq    = (const float*)d_in[9];
  const float* Wk    = (const float*)d_in[10];
  const float* Wv    = (const float*)d_in[11];
  const float* Wo    = (const float*)d_in[12];
  const float* bo    = (const float*)d_in[13];
  const float* Wa0   = (const float*)d_in[14];
  const float* ba0   = (const float*)d_in[15];
  const float* Wa1   = (const float*)d_in[16];
  const float* ba1   = (const float*)d_in[17];
  const float* Wa2   = (const float*)d_in[18];
  const float* ba2   = (const float*)d_in[19];
  const float* Wb0   = (const float*)d_in[20];
  const float* bb0   = (const float*)d_in[21];
  const float* Wb1   = (const float*)d_in[22];
  const float* bb1   = (const float*)d_in[23];
  const float* W_out = (const float*)d_in[24];
  const float* b_out = (const float*)d_in[25];

  char* ws = (char*)d_ws;
  size_t off = 0;
  auto alloc = [&](size_t bytes) { size_t r = off; off += (bytes + 255) & ~(size_t)255; return r; };

  u16* wt_c0  = (u16*)(ws + alloc((size_t)81 * 16384 * 2));
  u16* wt_c1  = (u16*)(ws + alloc((size_t)81 * 16384 * 2));
  u16* wt_q   = (u16*)(ws + alloc((size_t)3 * 16384 * 2));
  u16* wt_k   = (u16*)(ws + alloc((size_t)3 * 16384 * 2));
  u16* wt_v   = (u16*)(ws + alloc((size_t)3 * 16384 * 2));
  u16* wt_o   = (u16*)(ws + alloc((size_t)3 * 16384 * 2));
  u16* wt_a0  = (u16*)(ws + alloc((size_t)3 * 128 * 32 * 2));
  u16* wt_a1  = (u16*)(ws + alloc((size_t)81 * 32 * 32 * 2));
  u16* wt_a2  = (u16*)(ws + alloc((size_t)3 * 32 * 64 * 2));
  u16* wt_b0  = (u16*)(ws + alloc((size_t)81 * 128 * 32 * 2));
  u16* wt_b1  = (u16*)(ws + alloc((size_t)81 * 32 * 64 * 2));
  u16* wt_out = (u16*)(ws + alloc((size_t)27 * 16384 * 2));

  u16* B0 = (u16*)(ws + alloc((size_t)(NPTS + 1) * 128 * 2));  // "out" (gathered) — also AGG
  u16* B1 = (u16*)(ws + alloc((size_t)NPTS * 128 * 2));        // h (conv0 out)
  u16* KB = (u16*)(ws + alloc((size_t)(NPTS + 1) * 128 * 2));  // k-proj — also B2 (h2, gathered)
  u16* VB = (u16*)(ws + alloc((size_t)(NPTS + 1) * 128 * 2));  // v-proj — also B3 (x, gathered)
  u16* QB = (u16*)(ws + alloc((size_t)NPTS * 128 * 2));        // q-proj
  u16* H1 = (u16*)(ws + alloc((size_t)(NPTS + 1) * 32 * 2));   // a0 out (gathered)
  u16* HA = (u16*)(ws + alloc((size_t)NPTS * 32 * 2));         // a1 out
  u16* G  = (u16*)(ws + alloc((size_t)(NPTS + 1) * 32 * 2));   // b0 out (gathered)
  u16* AGG = B0;
  u16* B2 = KB;
  u16* B3 = VB;

  auto TG = [](int tot) { return (tot + 255) / 256; };
  // weight prep (bf16 + transpose)
  wtrans<<<TG(81 * 16384), 256, 0, stream>>>(W_c0, wt_c0, 81, 128, 128);
  wtrans<<<TG(81 * 16384), 256, 0, stream>>>(W_c1, wt_c1, 81, 128, 128);
  wtrans<<<TG(3 * 16384), 256, 0, stream>>>(Wq, wt_q, 3, 128, 128);
  wtrans<<<TG(3 * 16384), 256, 0, stream>>>(Wk, wt_k, 3, 128, 128);
  wtrans<<<TG(3 * 16384), 256, 0, stream>>>(Wv, wt_v, 3, 128, 128);
  wtrans<<<TG(3 * 16384), 256, 0, stream>>>(Wo, wt_o, 3, 128, 128);
  wtrans<<<TG(3 * 128 * 32), 256, 0, stream>>>(Wa0, wt_a0, 3, 128, 32);
  wtrans<<<TG(81 * 32 * 32), 256, 0, stream>>>(Wa1, wt_a1, 81, 32, 32);
  wtrans<<<TG(3 * 32 * 64), 256, 0, stream>>>(Wa2, wt_a2, 3, 32, 64);
  wtrans<<<TG(81 * 128 * 32), 256, 0, stream>>>(Wb0, wt_b0, 81, 128, 32);
  wtrans<<<TG(81 * 32 * 64), 256, 0, stream>>>(Wb1, wt_b1, 81, 32, 64);
  wtrans<<<TG(27 * 16384), 256, 0, stream>>>(W_out, wt_out, 27, 128, 128);

  zero_pads<<<1, 256, 0, stream>>>(B0 + (size_t)NPTS * 128, KB + (size_t)NPTS * 128,
                                   VB + (size_t)NPTS * 128, H1 + (size_t)NPTS * 32,
                                   G + (size_t)NPTS * 32);

  conv_in_k<<<NPTS * 128 / 256, 256, 0, stream>>>(feats, nbr, W_in, b_in, B0);

  const int GB = NPTS / 128;  // 512 blocks for sconv (512 threads each)
  for (int s = 0; s < 3; ++s) {
    const u16* wc0 = wt_c0 + (size_t)s * 27 * 16384;
    const u16* wc1 = wt_c1 + (size_t)s * 27 * 16384;
    const u16* wqs = wt_q + (size_t)s * 16384;
    const u16* wks = wt_k + (size_t)s * 16384;
    const u16* wvs = wt_v + (size_t)s * 16384;
    const u16* wos = wt_o + (size_t)s * 16384;
    const u16* wa0 = wt_a0 + (size_t)s * 4096;
    const u16* wa1 = wt_a1 + (size_t)s * 27648;
    const u16* wa2 = wt_a2 + (size_t)s * 2048;
    const u16* wb0 = wt_b0 + (size_t)s * 110592;
    const u16* wb1 = wt_b1 + (size_t)s * 55296;

    // h = sparse_conv(out, W_conv0)
    sconv<128, 128, 27, 0, false><<<GB, 512, 0, stream>>>(B0, nbr, wc0, b_c0 + s * 128, nullptr, 0, B1, 128);
    // q,k,v
    sconv<128, 128, 1, 0, false><<<GB, 512, 0, stream>>>(B1, nullptr, wqs, nullptr, nullptr, 0, QB, 128);
    sconv<128, 128, 1, 0, false><<<GB, 512, 0, stream>>>(B1, nullptr, wks, nullptr, nullptr, 0, KB, 128);
    sconv<128, 128, 1, 0, false><<<GB, 512, 0, stream>>>(B1, nullptr, wvs, nullptr, nullptr, 0, VB, 128);
    attn_k<<<NPTS / 4, 256, 0, stream>>>(QB, KB, VB, knn, AGG);
    // h2 = relu(h + agg@Wo + bo)
    sconv<128, 128, 1, 2, false><<<GB, 512, 0, stream>>>(AGG, nullptr, wos, bo + s * 128, B1, 128, B2, 128);
    // x = sparse_conv(h2, W_conv1)
    sconv<128, 128, 27, 0, false><<<GB, 512, 0, stream>>>(B2, nbr, wc1, b_c1 + s * 128, nullptr, 0, B3, 128);
    // irn
    sconv<128, 32, 1, 1, false><<<GB, 512, 0, stream>>>(B3, nullptr, wa0, ba0 + s * 32, nullptr, 0, H1, 32);
    sconv<32, 32, 27, 1, false><<<GB, 512, 0, stream>>>(H1, nbr, wa1, ba1 + s * 32, nullptr, 0, HA, 32);
    sconv<32, 64, 1, 3, false><<<GB, 512, 0, stream>>>(HA, nullptr, wa2, ba2 + s * 64, B3, 128, B0, 128);
    sconv<128, 32, 27, 1, false><<<GB, 512, 0, stream>>>(B3, nbr, wb0, bb0 + s * 32, nullptr, 0, G, 32);
    sconv<32, 64, 27, 3, false><<<GB, 512, 0, stream>>>(G, nbr, wb1, bb1 + s * 64, B3 + 64, 128, (void*)(B0 + 64), 128);
  }
  // final conv -> fp32 d_out
  sconv<128, 128, 27, 0, true><<<GB, 512, 0, stream>>>(B0, nbr, wt_out, b_out, nullptr, 0, d_out, 128);
}

// Round 4
// 1388.495 us; speedup vs baseline: 1.3665x; 1.3665x over previous
//
#include <hip/hip_runtime.h>
#include <stdint.h>

typedef unsigned short u16;
typedef __attribute__((ext_vector_type(8))) short bf16x8;
typedef __attribute__((ext_vector_type(4))) float f32x4;

#define NPTS 65536
#define NK27 27
#define KNN 16

__device__ __forceinline__ u16 f2b(float f) {
  union { float f; uint32_t u; } v; v.f = f;
  uint32_t r = (v.u + 0x7fffu + ((v.u >> 16) & 1u)) >> 16;
  return (u16)r;
}
__device__ __forceinline__ float b2f(u16 h) {
  union { uint32_t u; float f; } v; v.u = ((uint32_t)h) << 16; return v.f;
}

// dst[g][co][swz(ci)] (bf16) = src[g][ci][co] (f32); id is dst-linear.
// Swizzle: 16B-chunk c stored at c ^ (co & SWZB) so LDS reads are conflict-free.
__global__ __launch_bounds__(256) void wtrans(const float* __restrict__ src, u16* __restrict__ dst,
                                              int G, int CI, int CO) {
  int id = blockIdx.x * 256 + threadIdx.x;
  int tot = G * CI * CO;
  if (id >= tot) return;
  int cpr = CI / 8;
  int swzb = (cpr < 8 ? cpr : 8) - 1;
  int g = id / (CI * CO);
  int r = id - g * (CI * CO);
  int co = r / CI;
  int cis = r - co * CI;                    // swizzled ci position
  int c = cis / 8, e = cis - c * 8;
  int ci = (c ^ (co & swzb)) * 8 + e;       // source ci
  dst[id] = f2b(src[(size_t)g * CI * CO + (size_t)ci * CO + co]);
}

// idx transpose: out[k][n] = nbr[n][k]
__global__ __launch_bounds__(256) void itrans(const int* __restrict__ nbr, int* __restrict__ out) {
  int id = blockIdx.x * 256 + threadIdx.x;
  int k = id >> 16;          // / NPTS
  int n = id & (NPTS - 1);
  out[id] = nbr[n * NK27 + k];
}

__global__ void zero_pads(u16* a, u16* b, u16* c, u16* d, u16* e) {
  int t = threadIdx.x;
  if (t < 128) { a[t] = 0; b[t] = 0; c[t] = 0; }
  if (t < 32) { d[t] = 0; e[t] = 0; }
}

// out[n,co] = b[co] + sum_k feats[idx[n,k]] * W[k,0,co]   (idx==NPTS -> 0)
__global__ __launch_bounds__(256) void conv_in_k(const float* __restrict__ feats, const int* __restrict__ idx,
                                                 const float* __restrict__ W, const float* __restrict__ b,
                                                 u16* __restrict__ out) {
  int t = blockIdx.x * 256 + threadIdx.x;
  int n = t >> 7;
  int co = t & 127;
  float acc = b[co];
  for (int k = 0; k < NK27; ++k) {
    int m = idx[n * NK27 + k];
    float f = (m < NPTS) ? feats[m] : 0.0f;
    acc += f * W[k * 128 + co];
  }
  out[(size_t)n * 128 + co] = f2b(acc);
}

#define GLDS16(g, l)                                                                        \
  __builtin_amdgcn_global_load_lds((const __attribute__((address_space(1))) void*)(g),      \
                                   (__attribute__((address_space(3))) void*)(l), 16, 0, 0)

// Gathered GEMM, BM=256, 8 waves. A: global->VGPR direct (the gather IS the
// fragment load). B: global->LDS once per tap (double-buffered, swizzled store
// via pre-swizzled Wt; swizzled ds_read). idxt: [NK][NPTS] transposed indices.
// EMODE: 0=none 1=relu(v) 2=relu(v+res) 3=relu(v)+res
template<int CIN, int COUT, int NK, int EMODE, bool OUTF32>
__global__ __launch_bounds__(512, 2)
void sconv(const u16* __restrict__ x, const int* __restrict__ idxt,
           const u16* __restrict__ Wt, const float* __restrict__ bias,
           const u16* __restrict__ res, int res_stride,
           void* __restrict__ yout, int out_stride) {
  static_assert(NK == 1 || (NK & 1), "NK odd or 1");
  constexpr int BM = 256;
  constexpr int KK = CIN / 32;
  constexpr int CPR = CIN / 8;
  constexpr int SWZB = (CPR < 8 ? CPR : 8) - 1;
  constexpr int N_REP = COUT / 16;
  constexpr int M_REP = 2;                   // 32 rows per wave
  constexpr int BSZ = COUT * CIN;            // elements per tap of B
  constexpr int BCH = BSZ / 8;               // 16B chunks
  constexpr int BISS = (BCH + 511) / 512;    // stage rounds

  __shared__ __attribute__((aligned(16))) u16 Bs[2][BSZ];

  const int tid = threadIdx.x;
  const int lane = tid & 63;
  const int wave = tid >> 6;
  const int n0 = blockIdx.x * BM;
  const int lr = lane & 15;
  const int lh = lane >> 4;
  const int row0 = wave * 32;

  f32x4 acc[M_REP][N_REP];
#pragma unroll
  for (int i = 0; i < M_REP; ++i)
#pragma unroll
    for (int j = 0; j < N_REP; ++j) acc[i][j] = (f32x4){0.f, 0.f, 0.f, 0.f};

  bf16x8 A0[M_REP][KK], A1[M_REP][KK];
  int mn[M_REP];

  auto stageB = [&](int k) {
    const u16* src = Wt + (size_t)k * BSZ;
    u16* dst = &Bs[k & 1][0];
#pragma unroll
    for (int i = 0; i < BISS; ++i) {
      int cb = i * 512 + wave * 64;          // wave-uniform chunk base
      if (BCH % 512 == 0 || cb < BCH)
        GLDS16(src + (size_t)(cb + lane) * 8, dst + (size_t)cb * 8);
    }
  };
  auto loadIdx = [&](int k, int (&m)[M_REP]) {
#pragma unroll
    for (int mr = 0; mr < M_REP; ++mr)
      m[mr] = idxt[(size_t)k * NPTS + n0 + row0 + mr * 16 + lr];
  };
  auto issueA = [&](const int (&m)[M_REP], bf16x8 (&dst)[M_REP][KK]) {
#pragma unroll
    for (int mr = 0; mr < M_REP; ++mr)
#pragma unroll
      for (int kk = 0; kk < KK; ++kk)
        dst[mr][kk] = *(const bf16x8*)(x + (size_t)m[mr] * CIN + kk * 32 + lh * 8);
  };
  auto compute = [&](int buf, const bf16x8 (&AR)[M_REP][KK]) {
#pragma unroll
    for (int kk = 0; kk < KK; ++kk) {
      bf16x8 b[N_REP];
      int pc = (kk * 4 + lh) ^ (lr & SWZB);  // swizzled chunk (nr*16 preserves low 3 bits)
#pragma unroll
      for (int nr = 0; nr < N_REP; ++nr)
        b[nr] = *(const bf16x8*)(&Bs[buf][(nr * 16 + lr) * CIN + pc * 8]);
#pragma unroll
      for (int mr = 0; mr < M_REP; ++mr)
#pragma unroll
        for (int nr = 0; nr < N_REP; ++nr)
          acc[mr][nr] = __builtin_amdgcn_mfma_f32_16x16x32_bf16(AR[mr][kk], b[nr], acc[mr][nr], 0, 0, 0);
    }
  };

  // prologue: tap 0 into A0/Bs[0]; mn <- indices for tap 1
  {
    int m0[M_REP];
    if (NK == 1) {
#pragma unroll
      for (int mr = 0; mr < M_REP; ++mr) m0[mr] = n0 + row0 + mr * 16 + lr;
    } else {
      loadIdx(0, m0);
    }
    stageB(0);
    issueA(m0, A0);
    if (NK > 1) loadIdx(1, mn);
  }
  __syncthreads();

#define TAP(kv, AR, AW)                                                       \
  {                                                                           \
    const int k_ = (kv);                                                      \
    if (k_ + 1 < NK) {                                                        \
      stageB(k_ + 1);                                                         \
      issueA(mn, AW);                                                         \
      if (k_ + 2 < NK) loadIdx(k_ + 2, mn);                                   \
    }                                                                         \
    __builtin_amdgcn_sched_barrier(0);                                        \
    compute(k_ & 1, AR);                                                      \
    if (k_ + 1 < NK) __syncthreads();                                         \
  }

  if constexpr (NK == 1) {
    compute(0, A0);
  } else {
    int k = 0;
    for (; k + 2 < NK; k += 2) {
      TAP(k, A0, A1);
      TAP(k + 1, A1, A0);
    }
    TAP(k, A0, A1);  // NK odd: final tap, even parity -> A0
  }
#undef TAP

  // epilogue: C/D layout col=lane&15, row=(lane>>4)*4+j
#pragma unroll
  for (int mr = 0; mr < M_REP; ++mr) {
#pragma unroll
    for (int nr = 0; nr < N_REP; ++nr) {
      int col = nr * 16 + lr;
      float bv = bias ? bias[col] : 0.0f;
#pragma unroll
      for (int j = 0; j < 4; ++j) {
        int n = n0 + row0 + mr * 16 + lh * 4 + j;
        float v = acc[mr][nr][j] + bv;
        if (EMODE == 1) v = fmaxf(v, 0.0f);
        else if (EMODE == 2) v = fmaxf(v + b2f(res[(size_t)n * res_stride + col]), 0.0f);
        else if (EMODE == 3) v = fmaxf(v, 0.0f) + b2f(res[(size_t)n * res_stride + col]);
        if (OUTF32) ((float*)yout)[(size_t)n * out_stride + col] = v;
        else ((u16*)yout)[(size_t)n * out_stride + col] = f2b(v);
      }
    }
  }
}

// one wave per point: logits = (q . k_j)/sqrt(128); softmax; agg = sum a_j v_j
__global__ __launch_bounds__(256)
void attn_k(const u16* __restrict__ qb, const u16* __restrict__ kb,
            const u16* __restrict__ vb, const int* __restrict__ knn,
            u16* __restrict__ agg) {
  int n = (blockIdx.x * 256 + threadIdx.x) >> 6;
  int lane = threadIdx.x & 63;
  int c0 = lane * 2;
  uint32_t qp = *(const uint32_t*)(qb + (size_t)n * 128 + c0);
  float q0 = b2f((u16)(qp & 0xffff)), q1 = b2f((u16)(qp >> 16));
  float lg[KNN];
  int ms[KNN];
#pragma unroll
  for (int j = 0; j < KNN; ++j) {
    int m = knn[n * KNN + j];
    ms[j] = m;
    uint32_t kp = *(const uint32_t*)(kb + (size_t)m * 128 + c0);
    float p = q0 * b2f((u16)(kp & 0xffff)) + q1 * b2f((u16)(kp >> 16));
#pragma unroll
    for (int d = 1; d < 64; d <<= 1) p += __shfl_xor(p, d);
    lg[j] = p * 0.08838834764831845f;  // 128^-0.5
  }
  float mx = lg[0];
#pragma unroll
  for (int j = 1; j < KNN; ++j) mx = fmaxf(mx, lg[j]);
  float s = 0.f, w[KNN];
#pragma unroll
  for (int j = 0; j < KNN; ++j) { w[j] = __expf(lg[j] - mx); s += w[j]; }
  float inv = 1.0f / s;
  float a0 = 0.f, a1 = 0.f;
#pragma unroll
  for (int j = 0; j < KNN; ++j) {
    uint32_t vp = *(const uint32_t*)(vb + (size_t)ms[j] * 128 + c0);
    a0 += w[j] * b2f((u16)(vp & 0xffff));
    a1 += w[j] * b2f((u16)(vp >> 16));
  }
  a0 *= inv; a1 *= inv;
  uint32_t op = (uint32_t)f2b(a0) | ((uint32_t)f2b(a1) << 16);
  *(uint32_t*)(agg + (size_t)n * 128 + c0) = op;
}

extern "C" void kernel_launch(void* const* d_in, const int* in_sizes, int n_in,
                              void* d_out, int out_size, void* d_ws, size_t ws_size,
                              hipStream_t stream) {
  (void)in_sizes; (void)n_in; (void)out_size; (void)ws_size;
  const float* feats = (const float*)d_in[0];
  const int*   nbr   = (const int*)d_in[1];
  const int*   knn   = (const int*)d_in[2];
  const float* W_in  = (const float*)d_in[3];
  const float* b_in  = (const float*)d_in[4];
  const float* W_c0  = (const float*)d_in[5];
  const float* b_c0  = (const float*)d_in[6];
  const float* W_c1  = (const float*)d_in[7];
  const float* b_c1  = (const float*)d_in[8];
  const float* Wq    = (const float*)d_in[9];
  const float* Wk    = (const float*)d_in[10];
  const float* Wv    = (const float*)d_in[11];
  const float* Wo    = (const float*)d_in[12];
  const float* bo    = (const float*)d_in[13];
  const float* Wa0   = (const float*)d_in[14];
  const float* ba0   = (const float*)d_in[15];
  const float* Wa1   = (const float*)d_in[16];
  const float* ba1   = (const float*)d_in[17];
  const float* Wa2   = (const float*)d_in[18];
  const float* ba2   = (const float*)d_in[19];
  const float* Wb0   = (const float*)d_in[20];
  const float* bb0   = (const float*)d_in[21];
  const float* Wb1   = (const float*)d_in[22];
  const float* bb1   = (const float*)d_in[23];
  const float* W_out = (const float*)d_in[24];
  const float* b_out = (const float*)d_in[25];

  char* ws = (char*)d_ws;
  size_t off = 0;
  auto alloc = [&](size_t bytes) { size_t r = off; off += (bytes + 255) & ~(size_t)255; return r; };

  u16* wt_c0  = (u16*)(ws + alloc((size_t)81 * 16384 * 2));
  u16* wt_c1  = (u16*)(ws + alloc((size_t)81 * 16384 * 2));
  u16* wt_q   = (u16*)(ws + alloc((size_t)3 * 16384 * 2));
  u16* wt_k   = (u16*)(ws + alloc((size_t)3 * 16384 * 2));
  u16* wt_v   = (u16*)(ws + alloc((size_t)3 * 16384 * 2));
  u16* wt_o   = (u16*)(ws + alloc((size_t)3 * 16384 * 2));
  u16* wt_a0  = (u16*)(ws + alloc((size_t)3 * 128 * 32 * 2));
  u16* wt_a1  = (u16*)(ws + alloc((size_t)81 * 32 * 32 * 2));
  u16* wt_a2  = (u16*)(ws + alloc((size_t)3 * 32 * 64 * 2));
  u16* wt_b0  = (u16*)(ws + alloc((size_t)81 * 128 * 32 * 2));
  u16* wt_b1  = (u16*)(ws + alloc((size_t)81 * 32 * 64 * 2));
  u16* wt_out = (u16*)(ws + alloc((size_t)27 * 16384 * 2));
  int* idx_t  = (int*)(ws + alloc((size_t)NK27 * NPTS * 4));

  u16* B0 = (u16*)(ws + alloc((size_t)(NPTS + 1) * 128 * 2));  // "out" (gathered) — also AGG
  u16* B1 = (u16*)(ws + alloc((size_t)NPTS * 128 * 2));        // h (conv0 out)
  u16* KB = (u16*)(ws + alloc((size_t)(NPTS + 1) * 128 * 2));  // k-proj — also B2 (h2, gathered)
  u16* VB = (u16*)(ws + alloc((size_t)(NPTS + 1) * 128 * 2));  // v-proj — also B3 (x, gathered)
  u16* QB = (u16*)(ws + alloc((size_t)NPTS * 128 * 2));        // q-proj
  u16* H1 = (u16*)(ws + alloc((size_t)(NPTS + 1) * 32 * 2));   // a0 out (gathered)
  u16* HA = (u16*)(ws + alloc((size_t)NPTS * 32 * 2));         // a1 out
  u16* G  = (u16*)(ws + alloc((size_t)(NPTS + 1) * 32 * 2));   // b0 out (gathered)
  u16* AGG = B0;
  u16* B2 = KB;
  u16* B3 = VB;

  auto TG = [](int tot) { return (tot + 255) / 256; };
  // weight prep (bf16 + transpose + LDS swizzle)
  wtrans<<<TG(81 * 16384), 256, 0, stream>>>(W_c0, wt_c0, 81, 128, 128);
  wtrans<<<TG(81 * 16384), 256, 0, stream>>>(W_c1, wt_c1, 81, 128, 128);
  wtrans<<<TG(3 * 16384), 256, 0, stream>>>(Wq, wt_q, 3, 128, 128);
  wtrans<<<TG(3 * 16384), 256, 0, stream>>>(Wk, wt_k, 3, 128, 128);
  wtrans<<<TG(3 * 16384), 256, 0, stream>>>(Wv, wt_v, 3, 128, 128);
  wtrans<<<TG(3 * 16384), 256, 0, stream>>>(Wo, wt_o, 3, 128, 128);
  wtrans<<<TG(3 * 128 * 32), 256, 0, stream>>>(Wa0, wt_a0, 3, 128, 32);
  wtrans<<<TG(81 * 32 * 32), 256, 0, stream>>>(Wa1, wt_a1, 81, 32, 32);
  wtrans<<<TG(3 * 32 * 64), 256, 0, stream>>>(Wa2, wt_a2, 3, 32, 64);
  wtrans<<<TG(81 * 128 * 32), 256, 0, stream>>>(Wb0, wt_b0, 81, 128, 32);
  wtrans<<<TG(81 * 32 * 64), 256, 0, stream>>>(Wb1, wt_b1, 81, 32, 64);
  wtrans<<<TG(27 * 16384), 256, 0, stream>>>(W_out, wt_out, 27, 128, 128);
  itrans<<<NK27 * NPTS / 256, 256, 0, stream>>>(nbr, idx_t);

  zero_pads<<<1, 256, 0, stream>>>(B0 + (size_t)NPTS * 128, KB + (size_t)NPTS * 128,
                                   VB + (size_t)NPTS * 128, H1 + (size_t)NPTS * 32,
                                   G + (size_t)NPTS * 32);

  conv_in_k<<<NPTS * 128 / 256, 256, 0, stream>>>(feats, nbr, W_in, b_in, B0);

  const int GB = NPTS / 256;  // 256 blocks, 1/CU
  for (int s = 0; s < 3; ++s) {
    const u16* wc0 = wt_c0 + (size_t)s * 27 * 16384;
    const u16* wc1 = wt_c1 + (size_t)s * 27 * 16384;
    const u16* wqs = wt_q + (size_t)s * 16384;
    const u16* wks = wt_k + (size_t)s * 16384;
    const u16* wvs = wt_v + (size_t)s * 16384;
    const u16* wos = wt_o + (size_t)s * 16384;
    const u16* wa0 = wt_a0 + (size_t)s * 4096;
    const u16* wa1 = wt_a1 + (size_t)s * 27648;
    const u16* wa2 = wt_a2 + (size_t)s * 2048;
    const u16* wb0 = wt_b0 + (size_t)s * 110592;
    const u16* wb1 = wt_b1 + (size_t)s * 55296;

    // h = sparse_conv(out, W_conv0)
    sconv<128, 128, 27, 0, false><<<GB, 512, 0, stream>>>(B0, idx_t, wc0, b_c0 + s * 128, nullptr, 0, B1, 128);
    // q,k,v
    sconv<128, 128, 1, 0, false><<<GB, 512, 0, stream>>>(B1, nullptr, wqs, nullptr, nullptr, 0, QB, 128);
    sconv<128, 128, 1, 0, false><<<GB, 512, 0, stream>>>(B1, nullptr, wks, nullptr, nullptr, 0, KB, 128);
    sconv<128, 128, 1, 0, false><<<GB, 512, 0, stream>>>(B1, nullptr, wvs, nullptr, nullptr, 0, VB, 128);
    attn_k<<<NPTS / 4, 256, 0, stream>>>(QB, KB, VB, knn, AGG);
    // h2 = relu(h + agg@Wo + bo)
    sconv<128, 128, 1, 2, false><<<GB, 512, 0, stream>>>(AGG, nullptr, wos, bo + s * 128, B1, 128, B2, 128);
    // x = sparse_conv(h2, W_conv1)
    sconv<128, 128, 27, 0, false><<<GB, 512, 0, stream>>>(B2, idx_t, wc1, b_c1 + s * 128, nullptr, 0, B3, 128);
    // irn
    sconv<128, 32, 1, 1, false><<<GB, 512, 0, stream>>>(B3, nullptr, wa0, ba0 + s * 32, nullptr, 0, H1, 32);
    sconv<32, 32, 27, 1, false><<<GB, 512, 0, stream>>>(H1, idx_t, wa1, ba1 + s * 32, nullptr, 0, HA, 32);
    sconv<32, 64, 1, 3, false><<<GB, 512, 0, stream>>>(HA, nullptr, wa2, ba2 + s * 64, B3, 128, B0, 128);
    sconv<128, 32, 27, 1, false><<<GB, 512, 0, stream>>>(B3, idx_t, wb0, bb0 + s * 32, nullptr, 0, G, 32);
    sconv<32, 64, 27, 3, false><<<GB, 512, 0, stream>>>(G, idx_t, wb1, bb1 + s * 64, B3 + 64, 128, (void*)(B0 + 64), 128);
  }
  // final conv -> fp32 d_out
  sconv<128, 128, 27, 0, true><<<GB, 512, 0, stream>>>(B0, idx_t, wt_out, b_out, nullptr, 0, d_out, 128);
}